// Round 5
// baseline (232.538 us; speedup 1.0000x reference)
//
#include <hip/hip_runtime.h>
#include <hip/hip_bf16.h>

// LSTM cell, B=65536, I=H=128, fp32 I/O. gates = [x|h] @ [Wx|Wh]^T (+b) via
// bf16 MFMA (fp32 acc), fused elementwise LSTM epilogue.
// R5: NO LDS, NO BARRIERS. Each wave owns 32 batch rows x 128 gate-cols
// (all 4 gates x 32 hidden units of its jt quarter). A-fragments are loaded
// directly from global fp32 (2x dwordx4 per fragment; a wave consumes full
// 128B lines), converted to bf16 in-register. B-fragments come from the
// 256 KB L2-resident repacked weight buffer (d_ws). Pure dataflow -> the
// compiler software-pipelines loads across the fully unrolled K loop.
// XCD swizzle: the 4 jt-blocks sharing the same batch rows get blockIdx
// congruent mod 8 -> same XCD L2 -> x/h re-reads hit L2 instead of HBM.

typedef short s16x8 __attribute__((ext_vector_type(8)));
typedef float f32x4 __attribute__((ext_vector_type(4)));

__device__ __forceinline__ short f2bf(float f) {
    __hip_bfloat16 h = __float2bfloat16(f);
    return __builtin_bit_cast(short, h);
}
__device__ __forceinline__ float sigm(float x) { return 1.0f / (1.0f + __expf(-x)); }
__device__ __forceinline__ float tanh_f(float x) { return 1.0f - 2.0f / (1.0f + __expf(2.0f * x)); }

// ---- kernel 1: repack 8 fp32 weight mats -> bf16 fragment-ordered d_ws ----
// Chunk fi = (((jt*2+jh)*4+g)*2+half)*4+ks  (256 chunks x 64 lanes x 16B).
// Lane l holds W[j = jt*32+jh*16+(l&15)][k = (ks*4+(l>>4))*8 .. +8).
__global__ __launch_bounds__(256)
void repack_weights(const float* __restrict__ Wii, const float* __restrict__ Whi,
                    const float* __restrict__ Wif, const float* __restrict__ Whf,
                    const float* __restrict__ Wig, const float* __restrict__ Whg,
                    const float* __restrict__ Wio, const float* __restrict__ Who,
                    short* __restrict__ ws)
{
    const int t     = blockIdx.x * 256 + threadIdx.x;   // 16384 threads
    const int chunk = t >> 6;
    const int l     = t & 63;
    const int ks    = chunk & 3;
    const int half  = (chunk >> 2) & 1;
    const int g     = (chunk >> 3) & 3;
    const int jh    = (chunk >> 5) & 1;
    const int jt    = chunk >> 6;
    const int j     = jt * 32 + jh * 16 + (l & 15);
    const int k0    = (ks * 4 + (l >> 4)) * 8;

    const float* wp;
    if (half == 0) wp = (g == 0) ? Wii : (g == 1) ? Wif : (g == 2) ? Wig : Wio;
    else           wp = (g == 0) ? Whi : (g == 1) ? Whf : (g == 2) ? Whg : Who;

    const float* src = wp + (size_t)j * 128 + k0;
    f32x4 a = *(const f32x4*)src;
    f32x4 b = *(const f32x4*)(src + 4);
    s16x8 v;
#pragma unroll
    for (int k = 0; k < 4; ++k) { v[k] = f2bf(a[k]); v[4 + k] = f2bf(b[k]); }
    *(s16x8*)(ws + (size_t)t * 8) = v;
}

// ---- kernel 2: main fused LSTM, barrier-free ----
__global__ __launch_bounds__(256, 3)
void lstm_cell_kernel(const float* __restrict__ X,
                      const float* __restrict__ H,
                      const float* __restrict__ C,
                      const float* __restrict__ Bi, const float* __restrict__ Bf,
                      const float* __restrict__ Bg, const float* __restrict__ Bo,
                      const short* __restrict__ WS,
                      float* __restrict__ OutH,
                      float* __restrict__ OutC)
{
    const int tid = threadIdx.x;
    const int l  = tid & 63;
    const int wv = tid >> 6;     // wave -> 32-row group
    const int lj = l & 15;
    const int lq = l >> 4;

    // XCD swizzle: blocks sharing bb are congruent mod 8 -> same XCD.
    const unsigned u  = blockIdx.x;
    const int jt = (u >> 3) & 3;
    const int bb = (int)(((u >> 5) << 3) | (u & 7));
    const int B0 = bb * 128;
    const int J0 = jt * 32;
    const int R0 = B0 + wv * 32;          // this wave's row base

    f32x4 acc[2][8];                      // [mt][nt], nt = g*2 + jh
#pragma unroll
    for (int mt = 0; mt < 2; ++mt)
#pragma unroll
        for (int nt = 0; nt < 8; ++nt)
            acc[mt][nt] = (f32x4){0.f, 0.f, 0.f, 0.f};

    const short* wq = WS + (size_t)jt * 32768 + l * 8;   // jt: 64 chunks x 512 shorts

    // K loop: 2 halves x 4 k-steps of 32, fully unrolled, no barriers.
#pragma unroll
    for (int half = 0; half < 2; ++half) {
        const float* Asrc = half ? H : X;
#pragma unroll
        for (int ks = 0; ks < 4; ++ks) {
            // A fragments: direct global fp32 -> bf16
            s16x8 af[2];
#pragma unroll
            for (int mt = 0; mt < 2; ++mt) {
                const int row = R0 + mt * 16 + lj;
                const float* src = Asrc + (size_t)row * 128 + ks * 32 + lq * 8;
                f32x4 a = *(const f32x4*)src;
                f32x4 b = *(const f32x4*)(src + 4);
#pragma unroll
                for (int k = 0; k < 4; ++k) {
                    af[mt][k]     = f2bf(a[k]);
                    af[mt][4 + k] = f2bf(b[k]);
                }
            }
            // B fragments from repacked L2-resident buffer
            s16x8 bf[8];
#pragma unroll
            for (int nt = 0; nt < 8; ++nt) {
                const int jh = nt & 1, g = nt >> 1;
                bf[nt] = *(const s16x8*)(wq + (size_t)(jh * 32 + g * 8 + half * 4 + ks) * 512);
            }
#pragma unroll
            for (int mt = 0; mt < 2; ++mt)
#pragma unroll
                for (int nt = 0; nt < 8; ++nt)
                    acc[mt][nt] = __builtin_amdgcn_mfma_f32_16x16x32_bf16(
                        af[mt], bf[nt], acc[mt][nt], 0, 0, 0);
        }
    }

    // ---- epilogue: all 4 gates of (b,j) in this lane; fp32 I/O ----
#pragma unroll
    for (int jh = 0; jh < 2; ++jh) {
        const int j = J0 + jh * 16 + lj;
        const float bi  = Bi[j];
        const float bfv = Bf[j];
        const float bg  = Bg[j];
        const float bo  = Bo[j];
#pragma unroll
        for (int mt = 0; mt < 2; ++mt) {
#pragma unroll
            for (int r = 0; r < 4; ++r) {
                const int b = R0 + mt * 16 + lq * 4 + r;   // C/D: row=(lane>>4)*4+reg
                const size_t idx = (size_t)b * 128 + j;
                const float ia = acc[mt][0 * 2 + jh][r] + bi;
                const float fa = acc[mt][1 * 2 + jh][r] + bfv;
                const float ga = acc[mt][2 * 2 + jh][r] + bg;
                const float oa = acc[mt][3 * 2 + jh][r] + bo;
                const float it = sigm(ia);
                const float ft = sigm(fa);
                const float gt = tanh_f(ga);
                const float ot = sigm(oa);
                const float co = C[idx];
                const float cn = ft * co + it * gt;
                const float hn = ot * tanh_f(cn);
                OutH[idx] = hn;
                OutC[idx] = cn;
            }
        }
    }
}

extern "C" void kernel_launch(void* const* d_in, const int* in_sizes, int n_in,
                              void* d_out, int out_size, void* d_ws, size_t ws_size,
                              hipStream_t stream) {
    const float* X   = (const float*)d_in[0];
    const float* H   = (const float*)d_in[1];
    const float* C   = (const float*)d_in[2];
    const float* Wii = (const float*)d_in[3];
    const float* Whi = (const float*)d_in[4];
    const float* Bi  = (const float*)d_in[5];
    const float* Wif = (const float*)d_in[6];
    const float* Whf = (const float*)d_in[7];
    const float* Bf  = (const float*)d_in[8];
    const float* Wig = (const float*)d_in[9];
    const float* Whg = (const float*)d_in[10];
    const float* Bg  = (const float*)d_in[11];
    const float* Wio = (const float*)d_in[12];
    const float* Who = (const float*)d_in[13];
    const float* Bo  = (const float*)d_in[14];

    short* ws = (short*)d_ws;   // 256 KB bf16 fragment-ordered weights

    hipLaunchKernelGGL(repack_weights, dim3(64), dim3(256), 0, stream,
                       Wii, Whi, Wif, Whf, Wig, Whg, Wio, Who, ws);

    float* OutH = (float*)d_out;
    float* OutC = OutH + (size_t)65536 * 128;

    hipLaunchKernelGGL(lstm_cell_kernel, dim3(2048), dim3(256), 0, stream,
                       X, H, C, Bi, Bf, Bg, Bo, ws, OutH, OutC);
}